// Round 18
// baseline (209.723 us; speedup 1.0000x reference)
//
#include <hip/hip_runtime.h>

#define NB 8
#define CC 256
#define NN 4096
#define KVB 64
#define NT (NN / KVB)

typedef __attribute__((ext_vector_type(8))) __bf16 bf16x8;
typedef __attribute__((ext_vector_type(4))) float f32x4;
typedef unsigned short u16;
typedef unsigned int u32;

#define GLL(g, l) __builtin_amdgcn_global_load_lds(                         \
    (const __attribute__((address_space(1))) void*)(g),                     \
    (__attribute__((address_space(3))) void*)(l), 16, 0, 0)

static __device__ __forceinline__ u16 f2b(float f) {
  unsigned u = __float_as_uint(f);
  u += 0x7FFF + ((u >> 16) & 1);   // round-to-nearest-even
  return (u16)(u >> 16);
}

// v_permlane32_swap_b32 a, b: a_high32 <-> b_low32 (r6-verified).
static __device__ __forceinline__ void plswap(u32& a, u32& b) {
  asm volatile("v_permlane32_swap_b32 %0, %1" : "+v"(a), "+v"(b));
}
// v_permlane16_swap_b32: a_high16 <-> b_low16 within each 32-lane half (r13-verified).
static __device__ __forceinline__ void plswap16(u32& a, u32& b) {
  asm volatile("v_permlane16_swap_b32 %0, %1" : "+v"(a), "+v"(b));
}

// ---------------- kernel 1: convert weights to bf16
__global__ __launch_bounds__(256) void k_cvtw(const float* __restrict__ wq,
                                              const float* __restrict__ wk,
                                              const float* __restrict__ wv,
                                              u16* __restrict__ wb) {
  const int i = blockIdx.x * 256 + threadIdx.x;
  const int z = blockIdx.y;
  const float* s = z == 0 ? wq : (z == 1 ? wk : wv);
  wb[(size_t)z * CC * CC + i] = f2b(s[i]);
}

// ---------------- kernel 2: fused transpose + QKV projection
// s-outer restructure: av loaded ONCE per s (was 3x, once per z) — LDS reads
// 96 -> 32 per thread; 48-MFMA bursts across 3 independent accumulators.
// Accumulation order per acc[z] unchanged (s=0..7) => bit-identical results.
__global__ __launch_bounds__(256, 2) void k_qkv(const float* __restrict__ x,
                                                const u16* __restrict__ wb,
                                                const float* __restrict__ bq,
                                                const float* __restrict__ bk,
                                                const float* __restrict__ bv,
                                                u16* __restrict__ Qb,
                                                u16* __restrict__ Kb,
                                                u16* __restrict__ VTb) {
  __shared__ __align__(16) u16 At[64 * 256];   // rows 512B, XOR-swz ((n&7)<<4)

  const int b = blockIdx.y, n0 = blockIdx.x * 64;
  const int tid = threadIdx.x;
  const int wid = tid >> 6, lane = tid & 63;
  const int lr = lane & 15, lq = lane >> 4;

  // ---- phase 1: x (c-major) -> LDS transposed bf16 tile
  {
    const int ccol = (lane & 15) * 4;       // n-offset within tile (4 floats)
#pragma unroll
    for (int i = 0; i < 16; ++i) {
      const int c = wid * 64 + i * 4 + (lane >> 4);
      const f32x4 v = *(const f32x4*)(x + ((size_t)b * CC + c) * NN + n0 + ccol);
#pragma unroll
      for (int j = 0; j < 4; ++j) {
        const int nr = ccol + j;
        *(u16*)((char*)At + nr * 512 + ((c * 2) ^ ((nr & 7) << 4))) = f2b(v[j]);
      }
    }
  }
  __syncthreads();

  // ---- phase 2: three GEMMs off the LDS tile, s-outer
  const int i0 = wid * 64;
  f32x4 acc[3][4][4];
#pragma unroll
  for (int z = 0; z < 3; ++z)
#pragma unroll
    for (int mt = 0; mt < 4; ++mt)
#pragma unroll
      for (int it = 0; it < 4; ++it) acc[z][mt][it] = (f32x4){0.f, 0.f, 0.f, 0.f};

#pragma unroll
  for (int s = 0; s < 8; ++s) {
    const int kb2 = s * 64 + lq * 16;     // byte col offset
    bf16x8 av[4];
#pragma unroll
    for (int mt = 0; mt < 4; ++mt) {
      const int row = mt * 16 + lr;
      av[mt] = *(const bf16x8*)((const char*)At + row * 512 + (kb2 ^ ((row & 7) << 4)));
    }
#pragma unroll
    for (int z = 0; z < 3; ++z) {
      const u16* w = wb + (size_t)z * CC * CC;
      bf16x8 bm[4];
#pragma unroll
      for (int it = 0; it < 4; ++it)
        bm[it] = *(const bf16x8*)(w + (size_t)(i0 + it * 16 + lr) * CC + s * 32 + lq * 8);
#pragma unroll
      for (int mt = 0; mt < 4; ++mt)
#pragma unroll
        for (int it = 0; it < 4; ++it)
          acc[z][mt][it] = __builtin_amdgcn_mfma_f32_16x16x32_bf16(av[mt], bm[it], acc[z][mt][it], 0, 0, 0);
    }
  }

  // ---- epilogue per z (all indices static)
#pragma unroll
  for (int z = 0; z < 3; ++z) {
    const float* bias = z == 0 ? bq : (z == 1 ? bk : bv);
    const float sc = z == 0 ? 0.09016844136959962f : 1.0f;  // log2(e)/16
#pragma unroll
    for (int it = 0; it < 4; ++it) {
      const int i = i0 + it * 16 + lr;
      const float bb = bias[i];
#pragma unroll
      for (int mt = 0; mt < 4; ++mt) {
        f32x4 v = acc[z][mt][it];
        if (z == 2) {
          ushort4 p;
          p.x = f2b(v[0] + bb);
          p.y = f2b(v[1] + bb);
          p.z = f2b(v[2] + bb);
          p.w = f2b(v[3] + bb);
          *(ushort4*)(VTb + ((size_t)b * CC + i) * NN + n0 + mt * 16 + lq * 4) = p;
        } else {
          u16* O = (z == 0 ? Qb : Kb) + ((size_t)b * NN + n0 + mt * 16 + lq * 4) * CC + i;
#pragma unroll
          for (int r = 0; r < 4; ++r) O[(size_t)r * CC] = f2b((v[r] + bb) * sc);
        }
      }
    }
  }
}

// ---------------- kernel 3: flash attention (r17: best verified)
// 8 waves = 4qg x 2kvg; 32q x 32kv/wave/tile; KVB=64 dbuf; single barrier
// per tile; m=0 fixed-ref softmax; permlane16 dance; 4-deep VF prefetch;
// balanced c-split epilogue with static oacc indices.
__global__ __launch_bounds__(512, 2) void k_attn(const u16* __restrict__ Qb,
                                                 const u16* __restrict__ Kb,
                                                 const u16* __restrict__ VTb,
                                                 float* __restrict__ out) {
  __shared__ __align__(16) char smem[131072];
  __shared__ float l_s[2][128];

  const int bid = blockIdx.x;
  const int b = bid & 7;                 // batch -> XCD pin
  const int q0 = (bid >> 3) * 128;
  const int tid = threadIdx.x;
  const int wid = tid >> 6, lane = tid & 63;
  const int lr = lane & 15, lq = lane >> 4;
  const int kvg = wid & 1, qg = wid >> 1;

  const char* Kbase = (const char*)(Kb + (size_t)b * NN * CC);
  const char* Vbase = (const char*)(VTb + (size_t)b * CC * NN);

  const int kc0 = wid * 4;
  const int krow_off = lane >> 5;
  const int kbyt = (lane & 31) * 16;
  const int vrow_off = lane >> 3;
  const int vbyt = (lane & 7) * 16;

  auto stage = [&](int buf, int kv) {
#pragma unroll
    for (int i = 0; i < 4; ++i) {
      const int c = kc0 + i;
      const int row = c * 2 + krow_off;
      GLL(Kbase + (size_t)(kv + row) * (CC * 2) + (kbyt ^ ((row & 7) << 4)),
          smem + buf * 32768 + c * 1024);
      const int vr = c * 8 + vrow_off;
      GLL(Vbase + (size_t)vr * (NN * 2) + (size_t)kv * 2 + (vbyt ^ ((vr & 7) << 4)),
          smem + 65536 + buf * 32768 + c * 1024);
    }
  };

  // hoist Q (32 rows x 256, pre-scaled by log2e/16): qf[qt*8+s]
  bf16x8 qf[16];
  {
    const u16* Qp = Qb + ((size_t)b * NN + q0 + qg * 32 + lr) * CC + lq * 8;
#pragma unroll
    for (int qt = 0; qt < 2; ++qt)
#pragma unroll
      for (int s = 0; s < 8; ++s)
        qf[qt * 8 + s] = *(const bf16x8*)(Qp + (size_t)qt * 16 * CC + s * 32);
  }

  f32x4 oacc[2][16];
#pragma unroll
  for (int qt = 0; qt < 2; ++qt)
#pragma unroll
    for (int ct = 0; ct < 16; ++ct) oacc[qt][ct] = (f32x4){0.f, 0.f, 0.f, 0.f};
  float lpart[2] = {0.f, 0.f};

  f32x4 sacc[2][2];
  auto qk = [&](int buf) {
#pragma unroll
    for (int kvt = 0; kvt < 2; ++kvt)
#pragma unroll
      for (int qt = 0; qt < 2; ++qt) sacc[kvt][qt] = (f32x4){0.f, 0.f, 0.f, 0.f};
    __builtin_amdgcn_s_setprio(1);
#pragma unroll
    for (int s = 0; s < 8; ++s) {
      const int cb = s * 64 + lq * 16;
#pragma unroll
      for (int kvt = 0; kvt < 2; ++kvt) {
        const int row = kvg * 32 + kvt * 16 + lr;
        const bf16x8 kf = *(const bf16x8*)(smem + buf * 32768 +
                                           row * 512 + (cb ^ ((row & 7) << 4)));
        sacc[kvt][0] = __builtin_amdgcn_mfma_f32_16x16x32_bf16(kf, qf[s], sacc[kvt][0], 0, 0, 0);
        sacc[kvt][1] = __builtin_amdgcn_mfma_f32_16x16x32_bf16(kf, qf[8 + s], sacc[kvt][1], 0, 0, 0);
      }
    }
    __builtin_amdgcn_s_setprio(0);
  };

  // ---- prologue
  stage(0, 0);
  asm volatile("s_waitcnt vmcnt(0)" ::: "memory");
  __builtin_amdgcn_s_barrier();
  stage(1, KVB);
  qk(0);

  for (int t = 0; t < NT; ++t) {
    const int cur = t & 1;

    // ---- SM(t): P = 2^S (fixed m=0) + pack (sacc dies here)
    u32 w2q[2][4];
#pragma unroll
    for (int qt = 0; qt < 2; ++qt) {
#pragma unroll
      for (int kvt = 0; kvt < 2; ++kvt) {
        const float p0 = __builtin_amdgcn_exp2f(sacc[kvt][qt][0]);
        const float p1 = __builtin_amdgcn_exp2f(sacc[kvt][qt][1]);
        const float p2 = __builtin_amdgcn_exp2f(sacc[kvt][qt][2]);
        const float p3 = __builtin_amdgcn_exp2f(sacc[kvt][qt][3]);
        lpart[qt] += (p0 + p1) + (p2 + p3);
        const __bf16 b0 = (__bf16)p0, b1 = (__bf16)p1, b2 = (__bf16)p2, b3 = (__bf16)p3;
        w2q[qt][kvt * 2]     = (u32)__builtin_bit_cast(u16, b0) | ((u32)__builtin_bit_cast(u16, b1) << 16);
        w2q[qt][kvt * 2 + 1] = (u32)__builtin_bit_cast(u16, b2) | ((u32)__builtin_bit_cast(u16, b3) << 16);
      }
    }

    // ---- VF prefetch x4 (reuses sacc's dead registers)
    bf16x8 vfr[4];
#pragma unroll
    for (int ct = 0; ct < 4; ++ct) {
      const int row = ct * 16 + lr;
      vfr[ct] = *(const bf16x8*)(smem + 65536 + cur * 32768 + row * 128 +
                                 ((kvg * 64 + lq * 16) ^ ((row & 7) << 4)));
    }

    // ---- dance: plswap32 then plswap16 -> (pa_h, pa_2h) directly
    union { u32 u[4]; bf16x8 v; } pa[2];
#pragma unroll
    for (int qt = 0; qt < 2; ++qt) {
#pragma unroll
      for (int h = 0; h < 2; ++h) {
        u32 A = w2q[qt][h], B = w2q[qt][2 + h];
        plswap(A, B);
        plswap16(A, B);
        pa[qt].u[h] = A;
        pa[qt].u[2 + h] = B;
      }
    }

    // ---- PV(t): O += P V from Vt[cur]; each vf feeds 2 MFMAs
    __builtin_amdgcn_s_setprio(1);
#pragma unroll
    for (int ct = 0; ct < 16; ++ct) {
      const int row = ct * 16 + lr;
      const bf16x8 vf = (ct < 4) ? vfr[ct]
          : *(const bf16x8*)(smem + 65536 + cur * 32768 + row * 128 +
                             ((kvg * 64 + lq * 16) ^ ((row & 7) << 4)));
      oacc[0][ct] = __builtin_amdgcn_mfma_f32_16x16x32_bf16(pa[0].v, vf, oacc[0][ct], 0, 0, 0);
      oacc[1][ct] = __builtin_amdgcn_mfma_f32_16x16x32_bf16(pa[1].v, vf, oacc[1][ct], 0, 0, 0);
    }
    __builtin_amdgcn_s_setprio(0);

    // ---- single sync point: stage(t+1) landed everywhere, PV(t) reads done
    asm volatile("" ::: "memory");
    asm volatile("s_waitcnt vmcnt(0)" ::: "memory");
    __builtin_amdgcn_s_barrier();

    if (t < NT - 1) {
      if (t < NT - 2) stage(cur, (t + 2) * KVB);
      qk(cur ^ 1);
    }
  }

  // ---- epilogue (balanced, STATIC indices): reduce l + publish + write
  // other-half partials, ONE sync, then each group merges+stores its half.
#pragma unroll
  for (int qt = 0; qt < 2; ++qt) {
    lpart[qt] += __shfl_xor(lpart[qt], 16);
    lpart[qt] += __shfl_xor(lpart[qt], 32);
  }
  if (lq == 0) {
    l_s[kvg][qg * 32 + lr] = lpart[0];
    l_s[kvg][qg * 32 + 16 + lr] = lpart[1];
  }
  if (kvg == 1) {   // writes partials for c-half ct 0..7 (all indices literal)
#pragma unroll
    for (int qt = 0; qt < 2; ++qt)
#pragma unroll
      for (int ct = 0; ct < 8; ++ct) {
        const int row = ct * 16 + lr;
        *(f32x4*)(smem + qg * 32768 + row * 128 +
                  ((qt * 64 + lq * 16) ^ ((row & 7) << 4))) = oacc[qt][ct];
      }
  } else {          // writes partials for c-half ct 8..15 (all indices literal)
#pragma unroll
    for (int qt = 0; qt < 2; ++qt)
#pragma unroll
      for (int j = 0; j < 8; ++j) {
        const int ct = 8 + j;
        const int row = ct * 16 + lr;
        *(f32x4*)(smem + qg * 32768 + row * 128 +
                  ((qt * 64 + lq * 16) ^ ((row & 7) << 4))) = oacc[qt][ct];
      }
  }
  __syncthreads();  // stats + partner partials visible

  float linv[2][4];
#pragma unroll
  for (int qt = 0; qt < 2; ++qt)
#pragma unroll
    for (int r = 0; r < 4; ++r) {
      const int idx = qg * 32 + qt * 16 + lq * 4 + r;
      linv[qt][r] = 1.f / (l_s[0][idx] + l_s[1][idx]);
    }

  float* op = out + (size_t)b * CC * NN;
  if (kvg == 0) {   // merge+store ct 0..7 (static)
#pragma unroll
    for (int qt = 0; qt < 2; ++qt)
#pragma unroll
      for (int ct = 0; ct < 8; ++ct) {
        const int row = ct * 16 + lr;
        const f32x4 o1 = *(const f32x4*)(smem + qg * 32768 + row * 128 +
                                         ((qt * 64 + lq * 16) ^ ((row & 7) << 4)));
        f32x4 v = {(oacc[qt][ct][0] + o1[0]) * linv[qt][0],
                   (oacc[qt][ct][1] + o1[1]) * linv[qt][1],
                   (oacc[qt][ct][2] + o1[2]) * linv[qt][2],
                   (oacc[qt][ct][3] + o1[3]) * linv[qt][3]};
        *(f32x4*)(op + (size_t)row * NN + q0 + qg * 32 + qt * 16 + lq * 4) = v;
      }
  } else {          // merge+store ct 8..15 (static)
#pragma unroll
    for (int qt = 0; qt < 2; ++qt)
#pragma unroll
      for (int j = 0; j < 8; ++j) {
        const int ct = 8 + j;
        const int row = ct * 16 + lr;
        const f32x4 o1 = *(const f32x4*)(smem + qg * 32768 + row * 128 +
                                         ((qt * 64 + lq * 16) ^ ((row & 7) << 4)));
        f32x4 v = {(oacc[qt][ct][0] + o1[0]) * linv[qt][0],
                   (oacc[qt][ct][1] + o1[1]) * linv[qt][1],
                   (oacc[qt][ct][2] + o1[2]) * linv[qt][2],
                   (oacc[qt][ct][3] + o1[3]) * linv[qt][3]};
        *(f32x4*)(op + (size_t)row * NN + q0 + qg * 32 + qt * 16 + lq * 4) = v;
      }
  }
}

extern "C" void kernel_launch(void* const* d_in, const int* in_sizes, int n_in,
                              void* d_out, int out_size, void* d_ws, size_t ws_size,
                              hipStream_t stream) {
  const float* x = (const float*)d_in[0];
  const float* wq = (const float*)d_in[1];
  const float* wk = (const float*)d_in[2];
  const float* wv = (const float*)d_in[3];
  const float* bq = (const float*)d_in[4];
  const float* bk = (const float*)d_in[5];
  const float* bv = (const float*)d_in[6];
  float* out = (float*)d_out;

  u16* Qb = (u16*)d_ws;
  u16* Kb = Qb + (size_t)NB * NN * CC;
  u16* VTb = Kb + (size_t)NB * NN * CC;
  u16* wb = VTb + (size_t)NB * NN * CC;

  k_cvtw<<<dim3(CC * CC / 256, 3), 256, 0, stream>>>(wq, wk, wv, wb);
  k_qkv<<<dim3(NN / 64, NB), 256, 0, stream>>>(x, wb, bq, bk, bv, Qb, Kb, VTb);
  k_attn<<<dim3(NN / 128 * NB), 512, 0, stream>>>(Qb, Kb, VTb, out);
}

// Round 19
// 205.539 us; speedup vs baseline: 1.0204x; 1.0204x over previous
//
#include <hip/hip_runtime.h>

#define NB 8
#define CC 256
#define NN 4096
#define KVB 64
#define NT (NN / KVB)

typedef __attribute__((ext_vector_type(8))) __bf16 bf16x8;
typedef __attribute__((ext_vector_type(4))) float f32x4;
typedef unsigned short u16;
typedef unsigned int u32;

#define GLL(g, l) __builtin_amdgcn_global_load_lds(                         \
    (const __attribute__((address_space(1))) void*)(g),                     \
    (__attribute__((address_space(3))) void*)(l), 16, 0, 0)

static __device__ __forceinline__ u16 f2b(float f) {
  unsigned u = __float_as_uint(f);
  u += 0x7FFF + ((u >> 16) & 1);   // round-to-nearest-even
  return (u16)(u >> 16);
}

// v_permlane32_swap_b32 a, b: a_high32 <-> b_low32 (r6-verified).
static __device__ __forceinline__ void plswap(u32& a, u32& b) {
  asm volatile("v_permlane32_swap_b32 %0, %1" : "+v"(a), "+v"(b));
}
// v_permlane16_swap_b32: a_high16 <-> b_low16 within each 32-lane half (r13-verified).
static __device__ __forceinline__ void plswap16(u32& a, u32& b) {
  asm volatile("v_permlane16_swap_b32 %0, %1" : "+v"(a), "+v"(b));
}

// ---------------- kernel 1: convert weights to bf16
__global__ __launch_bounds__(256) void k_cvtw(const float* __restrict__ wq,
                                              const float* __restrict__ wk,
                                              const float* __restrict__ wv,
                                              u16* __restrict__ wb) {
  const int i = blockIdx.x * 256 + threadIdx.x;
  const int z = blockIdx.y;
  const float* s = z == 0 ? wq : (z == 1 ? wk : wv);
  wb[(size_t)z * CC * CC + i] = f2b(s[i]);
}

// ---------------- kernel 2: fused transpose + QKV projection (r17 z-outer —
// r18's s-outer raised VGPR pressure and regressed; reverted)
__global__ __launch_bounds__(256) void k_qkv(const float* __restrict__ x,
                                             const u16* __restrict__ wb,
                                             const float* __restrict__ bq,
                                             const float* __restrict__ bk,
                                             const float* __restrict__ bv,
                                             u16* __restrict__ Qb,
                                             u16* __restrict__ Kb,
                                             u16* __restrict__ VTb) {
  __shared__ __align__(16) u16 At[64 * 256];   // rows 512B, XOR-swz ((n&7)<<4)

  const int b = blockIdx.y, n0 = blockIdx.x * 64;
  const int tid = threadIdx.x;
  const int wid = tid >> 6, lane = tid & 63;
  const int lr = lane & 15, lq = lane >> 4;

  // ---- phase 1: x (c-major) -> LDS transposed bf16 tile
  {
    const int ccol = (lane & 15) * 4;       // n-offset within tile (4 floats)
#pragma unroll
    for (int i = 0; i < 16; ++i) {
      const int c = wid * 64 + i * 4 + (lane >> 4);
      const f32x4 v = *(const f32x4*)(x + ((size_t)b * CC + c) * NN + n0 + ccol);
#pragma unroll
      for (int j = 0; j < 4; ++j) {
        const int nr = ccol + j;
        *(u16*)((char*)At + nr * 512 + ((c * 2) ^ ((nr & 7) << 4))) = f2b(v[j]);
      }
    }
  }
  __syncthreads();

  // ---- phase 2: three GEMMs off the LDS tile
  const int i0 = wid * 64;
#pragma unroll
  for (int z = 0; z < 3; ++z) {
    const u16* w = wb + (size_t)z * CC * CC;
    const float* bias = z == 0 ? bq : (z == 1 ? bk : bv);
    const float sc = z == 0 ? 0.09016844136959962f : 1.0f;  // log2(e)/16

    f32x4 acc[4][4];
#pragma unroll
    for (int mt = 0; mt < 4; ++mt)
#pragma unroll
      for (int it = 0; it < 4; ++it) acc[mt][it] = (f32x4){0.f, 0.f, 0.f, 0.f};

#pragma unroll
    for (int s = 0; s < 8; ++s) {
      const int kb2 = s * 64 + lq * 16;     // byte col offset
      bf16x8 av[4], bm[4];
#pragma unroll
      for (int mt = 0; mt < 4; ++mt) {
        const int row = mt * 16 + lr;
        av[mt] = *(const bf16x8*)((const char*)At + row * 512 + (kb2 ^ ((row & 7) << 4)));
      }
#pragma unroll
      for (int it = 0; it < 4; ++it)
        bm[it] = *(const bf16x8*)(w + (size_t)(i0 + it * 16 + lr) * CC + s * 32 + lq * 8);
#pragma unroll
      for (int mt = 0; mt < 4; ++mt)
#pragma unroll
        for (int it = 0; it < 4; ++it)
          acc[mt][it] = __builtin_amdgcn_mfma_f32_16x16x32_bf16(av[mt], bm[it], acc[mt][it], 0, 0, 0);
    }

#pragma unroll
    for (int it = 0; it < 4; ++it) {
      const int i = i0 + it * 16 + lr;
      const float bb = bias[i];
#pragma unroll
      for (int mt = 0; mt < 4; ++mt) {
        f32x4 v = acc[mt][it];
        if (z == 2) {
          ushort4 p;
          p.x = f2b(v[0] + bb);
          p.y = f2b(v[1] + bb);
          p.z = f2b(v[2] + bb);
          p.w = f2b(v[3] + bb);
          *(ushort4*)(VTb + ((size_t)b * CC + i) * NN + n0 + mt * 16 + lq * 4) = p;
        } else {
          u16* O = (z == 0 ? Qb : Kb) + ((size_t)b * NN + n0 + mt * 16 + lq * 4) * CC + i;
#pragma unroll
          for (int r = 0; r < 4; ++r) O[(size_t)r * CC] = f2b((v[r] + bb) * sc);
        }
      }
    }
  }
}

// ---------------- kernel 3: flash attention (r17: best verified)
// 8 waves = 4qg x 2kvg; 32q x 32kv/wave/tile; KVB=64 dbuf; single barrier
// per tile; m=0 fixed-ref softmax; permlane16 dance; 4-deep VF prefetch;
// balanced c-split epilogue with static oacc indices.
__global__ __launch_bounds__(512, 2) void k_attn(const u16* __restrict__ Qb,
                                                 const u16* __restrict__ Kb,
                                                 const u16* __restrict__ VTb,
                                                 float* __restrict__ out) {
  __shared__ __align__(16) char smem[131072];
  __shared__ float l_s[2][128];

  const int bid = blockIdx.x;
  const int b = bid & 7;                 // batch -> XCD pin
  const int q0 = (bid >> 3) * 128;
  const int tid = threadIdx.x;
  const int wid = tid >> 6, lane = tid & 63;
  const int lr = lane & 15, lq = lane >> 4;
  const int kvg = wid & 1, qg = wid >> 1;

  const char* Kbase = (const char*)(Kb + (size_t)b * NN * CC);
  const char* Vbase = (const char*)(VTb + (size_t)b * CC * NN);

  const int kc0 = wid * 4;
  const int krow_off = lane >> 5;
  const int kbyt = (lane & 31) * 16;
  const int vrow_off = lane >> 3;
  const int vbyt = (lane & 7) * 16;

  auto stage = [&](int buf, int kv) {
#pragma unroll
    for (int i = 0; i < 4; ++i) {
      const int c = kc0 + i;
      const int row = c * 2 + krow_off;
      GLL(Kbase + (size_t)(kv + row) * (CC * 2) + (kbyt ^ ((row & 7) << 4)),
          smem + buf * 32768 + c * 1024);
      const int vr = c * 8 + vrow_off;
      GLL(Vbase + (size_t)vr * (NN * 2) + (size_t)kv * 2 + (vbyt ^ ((vr & 7) << 4)),
          smem + 65536 + buf * 32768 + c * 1024);
    }
  };

  // hoist Q (32 rows x 256, pre-scaled by log2e/16): qf[qt*8+s]
  bf16x8 qf[16];
  {
    const u16* Qp = Qb + ((size_t)b * NN + q0 + qg * 32 + lr) * CC + lq * 8;
#pragma unroll
    for (int qt = 0; qt < 2; ++qt)
#pragma unroll
      for (int s = 0; s < 8; ++s)
        qf[qt * 8 + s] = *(const bf16x8*)(Qp + (size_t)qt * 16 * CC + s * 32);
  }

  f32x4 oacc[2][16];
#pragma unroll
  for (int qt = 0; qt < 2; ++qt)
#pragma unroll
    for (int ct = 0; ct < 16; ++ct) oacc[qt][ct] = (f32x4){0.f, 0.f, 0.f, 0.f};
  float lpart[2] = {0.f, 0.f};

  f32x4 sacc[2][2];
  auto qk = [&](int buf) {
#pragma unroll
    for (int kvt = 0; kvt < 2; ++kvt)
#pragma unroll
      for (int qt = 0; qt < 2; ++qt) sacc[kvt][qt] = (f32x4){0.f, 0.f, 0.f, 0.f};
    __builtin_amdgcn_s_setprio(1);
#pragma unroll
    for (int s = 0; s < 8; ++s) {
      const int cb = s * 64 + lq * 16;
#pragma unroll
      for (int kvt = 0; kvt < 2; ++kvt) {
        const int row = kvg * 32 + kvt * 16 + lr;
        const bf16x8 kf = *(const bf16x8*)(smem + buf * 32768 +
                                           row * 512 + (cb ^ ((row & 7) << 4)));
        sacc[kvt][0] = __builtin_amdgcn_mfma_f32_16x16x32_bf16(kf, qf[s], sacc[kvt][0], 0, 0, 0);
        sacc[kvt][1] = __builtin_amdgcn_mfma_f32_16x16x32_bf16(kf, qf[8 + s], sacc[kvt][1], 0, 0, 0);
      }
    }
    __builtin_amdgcn_s_setprio(0);
  };

  // ---- prologue
  stage(0, 0);
  asm volatile("s_waitcnt vmcnt(0)" ::: "memory");
  __builtin_amdgcn_s_barrier();
  stage(1, KVB);
  qk(0);

  for (int t = 0; t < NT; ++t) {
    const int cur = t & 1;

    // ---- SM(t): P = 2^S (fixed m=0) + pack (sacc dies here)
    u32 w2q[2][4];
#pragma unroll
    for (int qt = 0; qt < 2; ++qt) {
#pragma unroll
      for (int kvt = 0; kvt < 2; ++kvt) {
        const float p0 = __builtin_amdgcn_exp2f(sacc[kvt][qt][0]);
        const float p1 = __builtin_amdgcn_exp2f(sacc[kvt][qt][1]);
        const float p2 = __builtin_amdgcn_exp2f(sacc[kvt][qt][2]);
        const float p3 = __builtin_amdgcn_exp2f(sacc[kvt][qt][3]);
        lpart[qt] += (p0 + p1) + (p2 + p3);
        const __bf16 b0 = (__bf16)p0, b1 = (__bf16)p1, b2 = (__bf16)p2, b3 = (__bf16)p3;
        w2q[qt][kvt * 2]     = (u32)__builtin_bit_cast(u16, b0) | ((u32)__builtin_bit_cast(u16, b1) << 16);
        w2q[qt][kvt * 2 + 1] = (u32)__builtin_bit_cast(u16, b2) | ((u32)__builtin_bit_cast(u16, b3) << 16);
      }
    }

    // ---- VF prefetch x4 (reuses sacc's dead registers)
    bf16x8 vfr[4];
#pragma unroll
    for (int ct = 0; ct < 4; ++ct) {
      const int row = ct * 16 + lr;
      vfr[ct] = *(const bf16x8*)(smem + 65536 + cur * 32768 + row * 128 +
                                 ((kvg * 64 + lq * 16) ^ ((row & 7) << 4)));
    }

    // ---- dance: plswap32 then plswap16 -> (pa_h, pa_2h) directly
    union { u32 u[4]; bf16x8 v; } pa[2];
#pragma unroll
    for (int qt = 0; qt < 2; ++qt) {
#pragma unroll
      for (int h = 0; h < 2; ++h) {
        u32 A = w2q[qt][h], B = w2q[qt][2 + h];
        plswap(A, B);
        plswap16(A, B);
        pa[qt].u[h] = A;
        pa[qt].u[2 + h] = B;
      }
    }

    // ---- PV(t): O += P V from Vt[cur]; each vf feeds 2 MFMAs
    __builtin_amdgcn_s_setprio(1);
#pragma unroll
    for (int ct = 0; ct < 16; ++ct) {
      const int row = ct * 16 + lr;
      const bf16x8 vf = (ct < 4) ? vfr[ct]
          : *(const bf16x8*)(smem + 65536 + cur * 32768 + row * 128 +
                             ((kvg * 64 + lq * 16) ^ ((row & 7) << 4)));
      oacc[0][ct] = __builtin_amdgcn_mfma_f32_16x16x32_bf16(pa[0].v, vf, oacc[0][ct], 0, 0, 0);
      oacc[1][ct] = __builtin_amdgcn_mfma_f32_16x16x32_bf16(pa[1].v, vf, oacc[1][ct], 0, 0, 0);
    }
    __builtin_amdgcn_s_setprio(0);

    // ---- single sync point: stage(t+1) landed everywhere, PV(t) reads done
    asm volatile("" ::: "memory");
    asm volatile("s_waitcnt vmcnt(0)" ::: "memory");
    __builtin_amdgcn_s_barrier();

    if (t < NT - 1) {
      if (t < NT - 2) stage(cur, (t + 2) * KVB);
      qk(cur ^ 1);
    }
  }

  // ---- epilogue (balanced, STATIC indices): reduce l + publish + write
  // other-half partials, ONE sync, then each group merges+stores its half.
#pragma unroll
  for (int qt = 0; qt < 2; ++qt) {
    lpart[qt] += __shfl_xor(lpart[qt], 16);
    lpart[qt] += __shfl_xor(lpart[qt], 32);
  }
  if (lq == 0) {
    l_s[kvg][qg * 32 + lr] = lpart[0];
    l_s[kvg][qg * 32 + 16 + lr] = lpart[1];
  }
  if (kvg == 1) {   // writes partials for c-half ct 0..7 (all indices literal)
#pragma unroll
    for (int qt = 0; qt < 2; ++qt)
#pragma unroll
      for (int ct = 0; ct < 8; ++ct) {
        const int row = ct * 16 + lr;
        *(f32x4*)(smem + qg * 32768 + row * 128 +
                  ((qt * 64 + lq * 16) ^ ((row & 7) << 4))) = oacc[qt][ct];
      }
  } else {          // writes partials for c-half ct 8..15 (all indices literal)
#pragma unroll
    for (int qt = 0; qt < 2; ++qt)
#pragma unroll
      for (int j = 0; j < 8; ++j) {
        const int ct = 8 + j;
        const int row = ct * 16 + lr;
        *(f32x4*)(smem + qg * 32768 + row * 128 +
                  ((qt * 64 + lq * 16) ^ ((row & 7) << 4))) = oacc[qt][ct];
      }
  }
  __syncthreads();  // stats + partner partials visible

  float linv[2][4];
#pragma unroll
  for (int qt = 0; qt < 2; ++qt)
#pragma unroll
    for (int r = 0; r < 4; ++r) {
      const int idx = qg * 32 + qt * 16 + lq * 4 + r;
      linv[qt][r] = 1.f / (l_s[0][idx] + l_s[1][idx]);
    }

  float* op = out + (size_t)b * CC * NN;
  if (kvg == 0) {   // merge+store ct 0..7 (static)
#pragma unroll
    for (int qt = 0; qt < 2; ++qt)
#pragma unroll
      for (int ct = 0; ct < 8; ++ct) {
        const int row = ct * 16 + lr;
        const f32x4 o1 = *(const f32x4*)(smem + qg * 32768 + row * 128 +
                                         ((qt * 64 + lq * 16) ^ ((row & 7) << 4)));
        f32x4 v = {(oacc[qt][ct][0] + o1[0]) * linv[qt][0],
                   (oacc[qt][ct][1] + o1[1]) * linv[qt][1],
                   (oacc[qt][ct][2] + o1[2]) * linv[qt][2],
                   (oacc[qt][ct][3] + o1[3]) * linv[qt][3]};
        *(f32x4*)(op + (size_t)row * NN + q0 + qg * 32 + qt * 16 + lq * 4) = v;
      }
  } else {          // merge+store ct 8..15 (static)
#pragma unroll
    for (int qt = 0; qt < 2; ++qt)
#pragma unroll
      for (int j = 0; j < 8; ++j) {
        const int ct = 8 + j;
        const int row = ct * 16 + lr;
        const f32x4 o1 = *(const f32x4*)(smem + qg * 32768 + row * 128 +
                                         ((qt * 64 + lq * 16) ^ ((row & 7) << 4)));
        f32x4 v = {(oacc[qt][ct][0] + o1[0]) * linv[qt][0],
                   (oacc[qt][ct][1] + o1[1]) * linv[qt][1],
                   (oacc[qt][ct][2] + o1[2]) * linv[qt][2],
                   (oacc[qt][ct][3] + o1[3]) * linv[qt][3]};
        *(f32x4*)(op + (size_t)row * NN + q0 + qg * 32 + qt * 16 + lq * 4) = v;
      }
  }
}

extern "C" void kernel_launch(void* const* d_in, const int* in_sizes, int n_in,
                              void* d_out, int out_size, void* d_ws, size_t ws_size,
                              hipStream_t stream) {
  const float* x = (const float*)d_in[0];
  const float* wq = (const float*)d_in[1];
  const float* wk = (const float*)d_in[2];
  const float* wv = (const float*)d_in[3];
  const float* bq = (const float*)d_in[4];
  const float* bk = (const float*)d_in[5];
  const float* bv = (const float*)d_in[6];
  float* out = (float*)d_out;

  u16* Qb = (u16*)d_ws;
  u16* Kb = Qb + (size_t)NB * NN * CC;
  u16* VTb = Kb + (size_t)NB * NN * CC;
  u16* wb = VTb + (size_t)NB * NN * CC;

  k_cvtw<<<dim3(CC * CC / 256, 3), 256, 0, stream>>>(wq, wk, wv, wb);
  k_qkv<<<dim3(NN / 64, NB), 256, 0, stream>>>(x, wb, bq, bk, bv, Qb, Kb, VTb);
  k_attn<<<dim3(NN / 128 * NB), 512, 0, stream>>>(Qb, Kb, VTb, out);
}

// Round 20
// 203.795 us; speedup vs baseline: 1.0291x; 1.0086x over previous
//
#include <hip/hip_runtime.h>

#define NB 8
#define CC 256
#define NN 4096
#define KVB 64
#define NT (NN / KVB)

typedef __attribute__((ext_vector_type(8))) __bf16 bf16x8;
typedef __attribute__((ext_vector_type(4))) float f32x4;
typedef unsigned short u16;
typedef unsigned int u32;

#define GLL(g, l) __builtin_amdgcn_global_load_lds(                         \
    (const __attribute__((address_space(1))) void*)(g),                     \
    (__attribute__((address_space(3))) void*)(l), 16, 0, 0)

static __device__ __forceinline__ u16 f2b(float f) {
  unsigned u = __float_as_uint(f);
  u += 0x7FFF + ((u >> 16) & 1);   // round-to-nearest-even
  return (u16)(u >> 16);
}

// v_permlane32_swap_b32 a, b: a_high32 <-> b_low32 (r6-verified).
static __device__ __forceinline__ void plswap(u32& a, u32& b) {
  asm volatile("v_permlane32_swap_b32 %0, %1" : "+v"(a), "+v"(b));
}
// v_permlane16_swap_b32: a_high16 <-> b_low16 within each 32-lane half (r13-verified).
static __device__ __forceinline__ void plswap16(u32& a, u32& b) {
  asm volatile("v_permlane16_swap_b32 %0, %1" : "+v"(a), "+v"(b));
}

// ---------------- kernel 1: convert weights to bf16
__global__ __launch_bounds__(256) void k_cvtw(const float* __restrict__ wq,
                                              const float* __restrict__ wk,
                                              const float* __restrict__ wv,
                                              u16* __restrict__ wb) {
  const int i = blockIdx.x * 256 + threadIdx.x;
  const int z = blockIdx.y;
  const float* s = z == 0 ? wq : (z == 1 ? wk : wv);
  wb[(size_t)z * CC * CC + i] = f2b(s[i]);
}

// ---------------- kernel 2: fused transpose + QKV projection (r17 z-outer;
// phase-1 writes pair-packed: 32x ds_write_b32 per thread instead of 64x
// ds_write_u16 — halves LDS write ops AND conflict degree ~16->8)
__global__ __launch_bounds__(256) void k_qkv(const float* __restrict__ x,
                                             const u16* __restrict__ wb,
                                             const float* __restrict__ bq,
                                             const float* __restrict__ bk,
                                             const float* __restrict__ bv,
                                             u16* __restrict__ Qb,
                                             u16* __restrict__ Kb,
                                             u16* __restrict__ VTb) {
  __shared__ __align__(16) u16 At[64 * 256];   // rows 512B, XOR-swz ((n&7)<<4)

  const int b = blockIdx.y, n0 = blockIdx.x * 64;
  const int tid = threadIdx.x;
  const int wid = tid >> 6, lane = tid & 63;
  const int lr = lane & 15, lq = lane >> 4;

  // ---- phase 1: x (c-major) -> LDS transposed bf16 tile, b32 pair writes
  {
    const int ccol = (lane & 15) * 4;       // n-offset within tile (4 floats)
#pragma unroll
    for (int i = 0; i < 8; ++i) {
      const int c0 = wid * 64 + i * 8 + (lane >> 4) * 2;   // even channel
      const float* xp = x + ((size_t)b * CC + c0) * NN + n0 + ccol;
      const f32x4 v0 = *(const f32x4*)(xp);        // channel c0, n..n+3
      const f32x4 v1 = *(const f32x4*)(xp + NN);   // channel c0+1
#pragma unroll
      for (int k = 0; k < 4; ++k) {
        const int nr = ccol + k;
        const u32 pw = (u32)f2b(v0[k]) | ((u32)f2b(v1[k]) << 16);
        *(u32*)((char*)At + nr * 512 + ((c0 * 2) ^ ((nr & 7) << 4))) = pw;
      }
    }
  }
  __syncthreads();

  // ---- phase 2: three GEMMs off the LDS tile
  const int i0 = wid * 64;
#pragma unroll
  for (int z = 0; z < 3; ++z) {
    const u16* w = wb + (size_t)z * CC * CC;
    const float* bias = z == 0 ? bq : (z == 1 ? bk : bv);
    const float sc = z == 0 ? 0.09016844136959962f : 1.0f;  // log2(e)/16

    f32x4 acc[4][4];
#pragma unroll
    for (int mt = 0; mt < 4; ++mt)
#pragma unroll
      for (int it = 0; it < 4; ++it) acc[mt][it] = (f32x4){0.f, 0.f, 0.f, 0.f};

#pragma unroll
    for (int s = 0; s < 8; ++s) {
      const int kb2 = s * 64 + lq * 16;     // byte col offset
      bf16x8 av[4], bm[4];
#pragma unroll
      for (int mt = 0; mt < 4; ++mt) {
        const int row = mt * 16 + lr;
        av[mt] = *(const bf16x8*)((const char*)At + row * 512 + (kb2 ^ ((row & 7) << 4)));
      }
#pragma unroll
      for (int it = 0; it < 4; ++it)
        bm[it] = *(const bf16x8*)(w + (size_t)(i0 + it * 16 + lr) * CC + s * 32 + lq * 8);
#pragma unroll
      for (int mt = 0; mt < 4; ++mt)
#pragma unroll
        for (int it = 0; it < 4; ++it)
          acc[mt][it] = __builtin_amdgcn_mfma_f32_16x16x32_bf16(av[mt], bm[it], acc[mt][it], 0, 0, 0);
    }

#pragma unroll
    for (int it = 0; it < 4; ++it) {
      const int i = i0 + it * 16 + lr;
      const float bb = bias[i];
#pragma unroll
      for (int mt = 0; mt < 4; ++mt) {
        f32x4 v = acc[mt][it];
        if (z == 2) {
          ushort4 p;
          p.x = f2b(v[0] + bb);
          p.y = f2b(v[1] + bb);
          p.z = f2b(v[2] + bb);
          p.w = f2b(v[3] + bb);
          *(ushort4*)(VTb + ((size_t)b * CC + i) * NN + n0 + mt * 16 + lq * 4) = p;
        } else {
          u16* O = (z == 0 ? Qb : Kb) + ((size_t)b * NN + n0 + mt * 16 + lq * 4) * CC + i;
#pragma unroll
          for (int r = 0; r < 4; ++r) O[(size_t)r * CC] = f2b((v[r] + bb) * sc);
        }
      }
    }
  }
}

// ---------------- kernel 3: flash attention (r17: best verified)
// 8 waves = 4qg x 2kvg; 32q x 32kv/wave/tile; KVB=64 dbuf; single barrier
// per tile; m=0 fixed-ref softmax; permlane16 dance; 4-deep VF prefetch;
// balanced c-split epilogue with static oacc indices.
__global__ __launch_bounds__(512, 2) void k_attn(const u16* __restrict__ Qb,
                                                 const u16* __restrict__ Kb,
                                                 const u16* __restrict__ VTb,
                                                 float* __restrict__ out) {
  __shared__ __align__(16) char smem[131072];
  __shared__ float l_s[2][128];

  const int bid = blockIdx.x;
  const int b = bid & 7;                 // batch -> XCD pin
  const int q0 = (bid >> 3) * 128;
  const int tid = threadIdx.x;
  const int wid = tid >> 6, lane = tid & 63;
  const int lr = lane & 15, lq = lane >> 4;
  const int kvg = wid & 1, qg = wid >> 1;

  const char* Kbase = (const char*)(Kb + (size_t)b * NN * CC);
  const char* Vbase = (const char*)(VTb + (size_t)b * CC * NN);

  const int kc0 = wid * 4;
  const int krow_off = lane >> 5;
  const int kbyt = (lane & 31) * 16;
  const int vrow_off = lane >> 3;
  const int vbyt = (lane & 7) * 16;

  auto stage = [&](int buf, int kv) {
#pragma unroll
    for (int i = 0; i < 4; ++i) {
      const int c = kc0 + i;
      const int row = c * 2 + krow_off;
      GLL(Kbase + (size_t)(kv + row) * (CC * 2) + (kbyt ^ ((row & 7) << 4)),
          smem + buf * 32768 + c * 1024);
      const int vr = c * 8 + vrow_off;
      GLL(Vbase + (size_t)vr * (NN * 2) + (size_t)kv * 2 + (vbyt ^ ((vr & 7) << 4)),
          smem + 65536 + buf * 32768 + c * 1024);
    }
  };

  // hoist Q (32 rows x 256, pre-scaled by log2e/16): qf[qt*8+s]
  bf16x8 qf[16];
  {
    const u16* Qp = Qb + ((size_t)b * NN + q0 + qg * 32 + lr) * CC + lq * 8;
#pragma unroll
    for (int qt = 0; qt < 2; ++qt)
#pragma unroll
      for (int s = 0; s < 8; ++s)
        qf[qt * 8 + s] = *(const bf16x8*)(Qp + (size_t)qt * 16 * CC + s * 32);
  }

  f32x4 oacc[2][16];
#pragma unroll
  for (int qt = 0; qt < 2; ++qt)
#pragma unroll
    for (int ct = 0; ct < 16; ++ct) oacc[qt][ct] = (f32x4){0.f, 0.f, 0.f, 0.f};
  float lpart[2] = {0.f, 0.f};

  f32x4 sacc[2][2];
  auto qk = [&](int buf) {
#pragma unroll
    for (int kvt = 0; kvt < 2; ++kvt)
#pragma unroll
      for (int qt = 0; qt < 2; ++qt) sacc[kvt][qt] = (f32x4){0.f, 0.f, 0.f, 0.f};
    __builtin_amdgcn_s_setprio(1);
#pragma unroll
    for (int s = 0; s < 8; ++s) {
      const int cb = s * 64 + lq * 16;
#pragma unroll
      for (int kvt = 0; kvt < 2; ++kvt) {
        const int row = kvg * 32 + kvt * 16 + lr;
        const bf16x8 kf = *(const bf16x8*)(smem + buf * 32768 +
                                           row * 512 + (cb ^ ((row & 7) << 4)));
        sacc[kvt][0] = __builtin_amdgcn_mfma_f32_16x16x32_bf16(kf, qf[s], sacc[kvt][0], 0, 0, 0);
        sacc[kvt][1] = __builtin_amdgcn_mfma_f32_16x16x32_bf16(kf, qf[8 + s], sacc[kvt][1], 0, 0, 0);
      }
    }
    __builtin_amdgcn_s_setprio(0);
  };

  // ---- prologue
  stage(0, 0);
  asm volatile("s_waitcnt vmcnt(0)" ::: "memory");
  __builtin_amdgcn_s_barrier();
  stage(1, KVB);
  qk(0);

  for (int t = 0; t < NT; ++t) {
    const int cur = t & 1;

    // ---- SM(t): P = 2^S (fixed m=0) + pack (sacc dies here)
    u32 w2q[2][4];
#pragma unroll
    for (int qt = 0; qt < 2; ++qt) {
#pragma unroll
      for (int kvt = 0; kvt < 2; ++kvt) {
        const float p0 = __builtin_amdgcn_exp2f(sacc[kvt][qt][0]);
        const float p1 = __builtin_amdgcn_exp2f(sacc[kvt][qt][1]);
        const float p2 = __builtin_amdgcn_exp2f(sacc[kvt][qt][2]);
        const float p3 = __builtin_amdgcn_exp2f(sacc[kvt][qt][3]);
        lpart[qt] += (p0 + p1) + (p2 + p3);
        const __bf16 b0 = (__bf16)p0, b1 = (__bf16)p1, b2 = (__bf16)p2, b3 = (__bf16)p3;
        w2q[qt][kvt * 2]     = (u32)__builtin_bit_cast(u16, b0) | ((u32)__builtin_bit_cast(u16, b1) << 16);
        w2q[qt][kvt * 2 + 1] = (u32)__builtin_bit_cast(u16, b2) | ((u32)__builtin_bit_cast(u16, b3) << 16);
      }
    }

    // ---- VF prefetch x4 (reuses sacc's dead registers)
    bf16x8 vfr[4];
#pragma unroll
    for (int ct = 0; ct < 4; ++ct) {
      const int row = ct * 16 + lr;
      vfr[ct] = *(const bf16x8*)(smem + 65536 + cur * 32768 + row * 128 +
                                 ((kvg * 64 + lq * 16) ^ ((row & 7) << 4)));
    }

    // ---- dance: plswap32 then plswap16 -> (pa_h, pa_2h) directly
    union { u32 u[4]; bf16x8 v; } pa[2];
#pragma unroll
    for (int qt = 0; qt < 2; ++qt) {
#pragma unroll
      for (int h = 0; h < 2; ++h) {
        u32 A = w2q[qt][h], B = w2q[qt][2 + h];
        plswap(A, B);
        plswap16(A, B);
        pa[qt].u[h] = A;
        pa[qt].u[2 + h] = B;
      }
    }

    // ---- PV(t): O += P V from Vt[cur]; each vf feeds 2 MFMAs
    __builtin_amdgcn_s_setprio(1);
#pragma unroll
    for (int ct = 0; ct < 16; ++ct) {
      const int row = ct * 16 + lr;
      const bf16x8 vf = (ct < 4) ? vfr[ct]
          : *(const bf16x8*)(smem + 65536 + cur * 32768 + row * 128 +
                             ((kvg * 64 + lq * 16) ^ ((row & 7) << 4)));
      oacc[0][ct] = __builtin_amdgcn_mfma_f32_16x16x32_bf16(pa[0].v, vf, oacc[0][ct], 0, 0, 0);
      oacc[1][ct] = __builtin_amdgcn_mfma_f32_16x16x32_bf16(pa[1].v, vf, oacc[1][ct], 0, 0, 0);
    }
    __builtin_amdgcn_s_setprio(0);

    // ---- single sync point: stage(t+1) landed everywhere, PV(t) reads done
    asm volatile("" ::: "memory");
    asm volatile("s_waitcnt vmcnt(0)" ::: "memory");
    __builtin_amdgcn_s_barrier();

    if (t < NT - 1) {
      if (t < NT - 2) stage(cur, (t + 2) * KVB);
      qk(cur ^ 1);
    }
  }

  // ---- epilogue (balanced, STATIC indices): reduce l + publish + write
  // other-half partials, ONE sync, then each group merges+stores its half.
#pragma unroll
  for (int qt = 0; qt < 2; ++qt) {
    lpart[qt] += __shfl_xor(lpart[qt], 16);
    lpart[qt] += __shfl_xor(lpart[qt], 32);
  }
  if (lq == 0) {
    l_s[kvg][qg * 32 + lr] = lpart[0];
    l_s[kvg][qg * 32 + 16 + lr] = lpart[1];
  }
  if (kvg == 1) {   // writes partials for c-half ct 0..7 (all indices literal)
#pragma unroll
    for (int qt = 0; qt < 2; ++qt)
#pragma unroll
      for (int ct = 0; ct < 8; ++ct) {
        const int row = ct * 16 + lr;
        *(f32x4*)(smem + qg * 32768 + row * 128 +
                  ((qt * 64 + lq * 16) ^ ((row & 7) << 4))) = oacc[qt][ct];
      }
  } else {          // writes partials for c-half ct 8..15 (all indices literal)
#pragma unroll
    for (int qt = 0; qt < 2; ++qt)
#pragma unroll
      for (int j = 0; j < 8; ++j) {
        const int ct = 8 + j;
        const int row = ct * 16 + lr;
        *(f32x4*)(smem + qg * 32768 + row * 128 +
                  ((qt * 64 + lq * 16) ^ ((row & 7) << 4))) = oacc[qt][ct];
      }
  }
  __syncthreads();  // stats + partner partials visible

  float linv[2][4];
#pragma unroll
  for (int qt = 0; qt < 2; ++qt)
#pragma unroll
    for (int r = 0; r < 4; ++r) {
      const int idx = qg * 32 + qt * 16 + lq * 4 + r;
      linv[qt][r] = 1.f / (l_s[0][idx] + l_s[1][idx]);
    }

  float* op = out + (size_t)b * CC * NN;
  if (kvg == 0) {   // merge+store ct 0..7 (static)
#pragma unroll
    for (int qt = 0; qt < 2; ++qt)
#pragma unroll
      for (int ct = 0; ct < 8; ++ct) {
        const int row = ct * 16 + lr;
        const f32x4 o1 = *(const f32x4*)(smem + qg * 32768 + row * 128 +
                                         ((qt * 64 + lq * 16) ^ ((row & 7) << 4)));
        f32x4 v = {(oacc[qt][ct][0] + o1[0]) * linv[qt][0],
                   (oacc[qt][ct][1] + o1[1]) * linv[qt][1],
                   (oacc[qt][ct][2] + o1[2]) * linv[qt][2],
                   (oacc[qt][ct][3] + o1[3]) * linv[qt][3]};
        *(f32x4*)(op + (size_t)row * NN + q0 + qg * 32 + qt * 16 + lq * 4) = v;
      }
  } else {          // merge+store ct 8..15 (static)
#pragma unroll
    for (int qt = 0; qt < 2; ++qt)
#pragma unroll
      for (int j = 0; j < 8; ++j) {
        const int ct = 8 + j;
        const int row = ct * 16 + lr;
        const f32x4 o1 = *(const f32x4*)(smem + qg * 32768 + row * 128 +
                                         ((qt * 64 + lq * 16) ^ ((row & 7) << 4)));
        f32x4 v = {(oacc[qt][ct][0] + o1[0]) * linv[qt][0],
                   (oacc[qt][ct][1] + o1[1]) * linv[qt][1],
                   (oacc[qt][ct][2] + o1[2]) * linv[qt][2],
                   (oacc[qt][ct][3] + o1[3]) * linv[qt][3]};
        *(f32x4*)(op + (size_t)row * NN + q0 + qg * 32 + qt * 16 + lq * 4) = v;
      }
  }
}

extern "C" void kernel_launch(void* const* d_in, const int* in_sizes, int n_in,
                              void* d_out, int out_size, void* d_ws, size_t ws_size,
                              hipStream_t stream) {
  const float* x = (const float*)d_in[0];
  const float* wq = (const float*)d_in[1];
  const float* wk = (const float*)d_in[2];
  const float* wv = (const float*)d_in[3];
  const float* bq = (const float*)d_in[4];
  const float* bk = (const float*)d_in[5];
  const float* bv = (const float*)d_in[6];
  float* out = (float*)d_out;

  u16* Qb = (u16*)d_ws;
  u16* Kb = Qb + (size_t)NB * NN * CC;
  u16* VTb = Kb + (size_t)NB * NN * CC;
  u16* wb = VTb + (size_t)NB * NN * CC;

  k_cvtw<<<dim3(CC * CC / 256, 3), 256, 0, stream>>>(wq, wk, wv, wb);
  k_qkv<<<dim3(NN / 64, NB), 256, 0, stream>>>(x, wb, bq, bk, bv, Qb, Kb, VTb);
  k_attn<<<dim3(NN / 128 * NB), 512, 0, stream>>>(Qb, Kb, VTb, out);
}